// Round 2
// baseline (434979.492 us; speedup 1.0000x reference)
//
#include <hip/hip_runtime.h>
#include <math.h>

#define NN 256
#define HH 64
#define SDIM 260

__device__ __forceinline__ float sigm(float x) { return 1.0f / (1.0f + expf(-x)); }

// Pout = I + (h/div) * A    (elementwise; h = tev[1]-tev[0])
__global__ void k_affine(const float* __restrict__ A, float* __restrict__ Pout,
                         const float* __restrict__ tev, int div)
{
    int i = blockIdx.x, j = threadIdx.x;
    double h = (double)tev[1] - (double)tev[0];
    double v = (i == j ? 1.0 : 0.0) + (h / (double)div) * (double)A[i * NN + j];
    Pout[i * NN + j] = (float)v;
}

// Pout = I + (h/div) * A @ Pin   (fp64 accumulate)
__global__ void k_gemm(const float* __restrict__ A, const float* __restrict__ Pin,
                       float* __restrict__ Pout, const float* __restrict__ tev, int div)
{
    int i = blockIdx.x, j = threadIdx.x;
    double h = (double)tev[1] - (double)tev[0];
    const float* Ar = A + i * NN;
    double acc = 0.0;
    for (int k = 0; k < NN; ++k) acc += (double)Ar[k] * (double)Pin[k * NN + j];
    double v = (i == j ? 1.0 : 0.0) + (h / (double)div) * acc;
    Pout[i * NN + j] = (float)v;
}

// gq = [g0 | g1 | g2 | g3 | q], each 256 floats.
__global__ void k_prep_vec(const float* __restrict__ A, const float* __restrict__ B,
                           const float* __restrict__ cooling, const float* __restrict__ tev,
                           float* __restrict__ gq)
{
    __shared__ float heat[NN];
    __shared__ float vin[NN];
    int t = threadIdx.x; // 256 threads
    double h = (double)tev[1] - (double)tev[0];
    heat[t] = (t < NN - 2) ? 500.0f * sigm(cooling[t]) : 0.0f;
    __syncthreads();
    float B0 = B[t * (NN - 1)];
    double bh = 0.0;
    for (int j = 0; j < NN - 2; ++j) bh += (double)B[t * (NN - 1) + 1 + j] * (double)heat[j];
    vin[t] = B0; __syncthreads();
    double v1 = 0.0; for (int k = 0; k < NN; ++k) v1 += (double)A[t * NN + k] * (double)vin[k];
    __syncthreads(); vin[t] = (float)v1; __syncthreads();
    double v2 = 0.0; for (int k = 0; k < NN; ++k) v2 += (double)A[t * NN + k] * (double)vin[k];
    __syncthreads(); vin[t] = (float)v2; __syncthreads();
    double v3 = 0.0; for (int k = 0; k < NN; ++k) v3 += (double)A[t * NN + k] * (double)vin[k];
    __syncthreads();
    vin[t] = (float)bh; __syncthreads();
    double u1 = 0.0; for (int k = 0; k < NN; ++k) u1 += (double)A[t * NN + k] * (double)vin[k];
    __syncthreads(); vin[t] = (float)u1; __syncthreads();
    double u2 = 0.0; for (int k = 0; k < NN; ++k) u2 += (double)A[t * NN + k] * (double)vin[k];
    __syncthreads(); vin[t] = (float)u2; __syncthreads();
    double u3 = 0.0; for (int k = 0; k < NN; ++k) u3 += (double)A[t * NN + k] * (double)vin[k];

    gq[t]        = (float)((h / 6.0) * (double)B0);
    gq[256 + t]  = (float)((h * h / 6.0) * v1);
    gq[512 + t]  = (float)((h * h * h / 12.0) * v2);
    gq[768 + t]  = (float)((h * h * h * h / 24.0) * v3);
    gq[1024 + t] = (float)(h * bh + (h * h / 2.0) * u1 + (h * h * h / 6.0) * u2
                           + (h * h * h * h / 24.0) * u3);
}

__device__ __forceinline__ float interp1(float x, const float* __restrict__ ts,
                                         const float* __restrict__ vs, int n)
{
    int lo = 0, hi = n;
    while (lo < hi) { int mid = (lo + hi) >> 1; if (ts[mid] <= x) lo = mid + 1; else hi = mid; }
    int i = lo; if (i < 1) i = 1; if (i > n - 1) i = n - 1;
    float xim = ts[i - 1], xi = ts[i];
    float fim = vs[i - 1], fi = vs[i];
    return fim + (x - xim) / (xi - xim) * (fi - fim);
}

// per-step time data: td[k][0..7] = {S0,S1,S2,S3, sinD,cosD,sinW,cosW}
__global__ void k_time(const float* __restrict__ tev, const float* __restrict__ tts,
                       const float* __restrict__ tvals, float* __restrict__ td,
                       int T, int ntout)
{
    int k = blockIdx.x * blockDim.x + threadIdx.x;
    if (k >= T) return;
    float t0 = tev[0];
    float dtf = tev[1] - t0;
    float t = tev[k] - t0;
    const float cD = (float)(2.0 * M_PI / 86400.0);
    const float cW = (float)(2.0 * M_PI / 604800.0);
    float f0 = (float)sin((double)(t * cD));
    float f1 = (float)cos((double)(t * cD));
    float f2 = (float)sin((double)(t * cW));
    float f3 = (float)cos((double)(t * cW));
    float To1 = interp1(t + t0, tts, tvals, ntout);
    float To2 = interp1((t + 0.5f * dtf) + t0, tts, tvals, ntout);
    float To4 = interp1((t + dtf) + t0, tts, tvals, ntout);
    size_t o = (size_t)k * 8;
    td[o + 0] = To1 + 4.0f * To2 + To4;
    td[o + 1] = To1 + 2.0f * To2;
    td[o + 2] = To1 + To2;
    td[o + 3] = To1;
    td[o + 4] = f0; td[o + 5] = f1; td[o + 6] = f2; td[o + 7] = f3;
}

// Sequential integrator: 1 block, 1024 threads (16 waves), R in VGPRs (64/thread).
// Per-thread register budget ~115 < 128 cap (4 waves/SIMD) -> no spill.
__global__ __launch_bounds__(1024, 1) void k_main(
    const float* __restrict__ tdata, const float* __restrict__ Rm,
    const float* __restrict__ gq, const float* __restrict__ w1g,
    const float* __restrict__ b1g, const float* __restrict__ w2g,
    float* __restrict__ out, int T)
{
    __shared__ __align__(16) float xbuf[NN];
    __shared__ __align__(16) float sbuf[NN];
    __shared__ float hid[HH];
    __shared__ float b1eff[HH];
    __shared__ __align__(16) float part[4][NN];
    __shared__ __align__(16) float td[2][8];

    const int t = threadIdx.x;
    const int r = t & 255;       // matvec row
    const int seg = t >> 8;      // 0..3 quarter of the row
    const int jr = t >> 4;       // policy row 0..63
    const int c0 = t & 15;       // policy column chunk (16 cols)
    const int lane = t & 63;

    // R quarter-row -> registers (64 floats)
    float Rreg[64];
    {
        const float* src = Rm + (size_t)r * NN + seg * 64;
        #pragma unroll
        for (int i = 0; i < 16; ++i) {
            float4 v = reinterpret_cast<const float4*>(src)[i];
            Rreg[4 * i + 0] = v.x; Rreg[4 * i + 1] = v.y;
            Rreg[4 * i + 2] = v.z; Rreg[4 * i + 3] = v.w;
        }
    }
    // policy weights: 16 state-cols per thread; feature cols folded into b1eff
    float w1reg[16];
    #pragma unroll
    for (int i = 0; i < 16; ++i) w1reg[i] = w1g[jr * SDIM + c0 * 16 + i];
    float w1f0 = 0.f, w1f1 = 0.f, w1f2 = 0.f, w1f3 = 0.f, b1r = 0.f;
    if (t < HH) {
        w1f0 = w1g[t * SDIM + 256]; w1f1 = w1g[t * SDIM + 257];
        w1f2 = w1g[t * SDIM + 258]; w1f3 = w1g[t * SDIM + 259];
        b1r  = b1g[t];
    }
    float w2r = w2g[lane];
    float g0r = gq[r], g1r = gq[256 + r], g2r = gq[512 + r], g3r = gq[768 + r];
    float qr  = gq[1024 + r];

    if (t < NN) { xbuf[t] = 26.0f; sbuf[t] = (26.0f - 23.359f) / 1.41f; }
    if (t < 8) td[0][t] = tdata[t];
    __syncthreads();
    if (t < HH)
        b1eff[t] = b1r + w1f0 * td[0][4] + w1f1 * td[0][5]
                 + w1f2 * td[0][6] + w1f3 * td[0][7];
    __syncthreads();

    for (int k = 0; k < T; ++k) {
        const int cur = k & 1, nxt = cur ^ 1;
        // prefetch next step's time data
        float tdp = 0.0f;
        if (t >= 1016 && k + 1 < T) tdp = tdata[(size_t)(k + 1) * 8 + (t - 1016)];

        // ---- Phase A: policy hidden + matvec partials + out write ----
        float hs = 0.0f;
        {
            const float4* sb4 = reinterpret_cast<const float4*>(sbuf + c0 * 16);
            #pragma unroll
            for (int i = 0; i < 4; ++i) {
                float4 sv = sb4[i];
                hs += w1reg[4 * i + 0] * sv.x + w1reg[4 * i + 1] * sv.y
                    + w1reg[4 * i + 2] * sv.z + w1reg[4 * i + 3] * sv.w;
            }
        }
        hs += __shfl_xor(hs, 1); hs += __shfl_xor(hs, 2);
        hs += __shfl_xor(hs, 4); hs += __shfl_xor(hs, 8);

        float a0 = 0.f, a1 = 0.f, a2 = 0.f, a3 = 0.f;
        {
            const float4* xb4 = reinterpret_cast<const float4*>(xbuf) + seg * 16;
            #pragma unroll
            for (int i = 0; i < 16; ++i) {
                float4 xv = xb4[i];
                a0 += Rreg[4 * i + 0] * xv.x;
                a1 += Rreg[4 * i + 1] * xv.y;
                a2 += Rreg[4 * i + 2] * xv.z;
                a3 += Rreg[4 * i + 3] * xv.w;
            }
        }
        if (c0 == 0) hid[jr] = tanhf(hs + b1eff[jr]);
        part[seg][r] = (a0 + a1) + (a2 + a3);
        if (t < NN) out[(size_t)k * NN + t] = xbuf[t];
        if (t >= 1016) td[nxt][t - 1016] = tdp;
        asm volatile("s_waitcnt lgkmcnt(0)\ns_barrier" ::: "memory");

        // ---- Phase B: action + combine (waves 0-3 redundantly reduce) ----
        if (t < NN) {
            float v = w2r * hid[lane];
            v += __shfl_xor(v, 1);  v += __shfl_xor(v, 2);  v += __shfl_xor(v, 4);
            v += __shfl_xor(v, 8);  v += __shfl_xor(v, 16); v += __shfl_xor(v, 32);
            float aS = sigm(v);
            float S0 = td[cur][0], S1 = td[cur][1], S2 = td[cur][2], S3 = td[cur][3];
            float y = (part[0][t] + part[1][t]) + (part[2][t] + part[3][t]);
            float xn = y + S0 * g0r + S1 * g1r + S2 * g2r + S3 * g3r - aS * qr;
            xbuf[t] = xn;
            sbuf[t] = (xn - 23.359f) / 1.41f;
        }
        if (t < HH && k + 1 < T)
            b1eff[t] = b1r + w1f0 * td[nxt][4] + w1f1 * td[nxt][5]
                     + w1f2 * td[nxt][6] + w1f3 * td[nxt][7];
        asm volatile("s_waitcnt lgkmcnt(0)\ns_barrier" ::: "memory");
    }
}

extern "C" void kernel_launch(void* const* d_in, const int* in_sizes, int n_in,
                              void* d_out, int out_size, void* d_ws, size_t ws_size,
                              hipStream_t stream)
{
    (void)n_in; (void)out_size; (void)ws_size;
    const float* tev     = (const float*)d_in[0];
    const float* A       = (const float*)d_in[1];
    const float* B       = (const float*)d_in[2];
    const float* cooling = (const float*)d_in[3];
    const float* w1      = (const float*)d_in[4];
    const float* b1      = (const float*)d_in[5];
    const float* w2      = (const float*)d_in[6];
    const float* tts     = (const float*)d_in[7];
    const float* tvals   = (const float*)d_in[8];
    const int T     = in_sizes[0];
    const int ntout = in_sizes[7];

    float* out = (float*)d_out;
    float* ws  = (float*)d_ws;
    float* R   = ws;                       // 65536
    float* gq  = ws + 65536;               // 1280
    float* td  = ws + 65536 + 1280;        // T*8
    float* P1 = out;                       // GEMM ping-pong scratch (rewritten later)
    float* P2 = out + 65536;

    hipLaunchKernelGGL(k_affine, dim3(256), dim3(256), 0, stream, A, P1, tev, 4);
    hipLaunchKernelGGL(k_gemm,   dim3(256), dim3(256), 0, stream, A, P1, P2, tev, 3);
    hipLaunchKernelGGL(k_gemm,   dim3(256), dim3(256), 0, stream, A, P2, P1, tev, 2);
    hipLaunchKernelGGL(k_gemm,   dim3(256), dim3(256), 0, stream, A, P1, R,  tev, 1);
    hipLaunchKernelGGL(k_prep_vec, dim3(1), dim3(256), 0, stream, A, B, cooling, tev, gq);
    hipLaunchKernelGGL(k_time, dim3((T + 255) / 256), dim3(256), 0, stream,
                       tev, tts, tvals, td, T, ntout);
    hipLaunchKernelGGL(k_main, dim3(1), dim3(1024), 0, stream,
                       td, R, gq, w1, b1, w2, out, T);
}

// Round 4
// 101312.561 us; speedup vs baseline: 4.2934x; 4.2934x over previous
//
#include <hip/hip_runtime.h>
#include <math.h>

#define NN 256
#define HH 64
#define W1STRIDE 276

typedef unsigned int uint32;

__device__ __forceinline__ float sigm(float x) { return 1.0f / (1.0f + expf(-x)); }

// ---------------- R construction (fp64 GEMM chain) — Round-2 proven ----------------
__global__ void k_affine(const float* __restrict__ A, float* __restrict__ Pout,
                         const float* __restrict__ tev, int div)
{
    int i = blockIdx.x, j = threadIdx.x;
    double h = (double)tev[1] - (double)tev[0];
    double v = (i == j ? 1.0 : 0.0) + (h / (double)div) * (double)A[i * NN + j];
    Pout[i * NN + j] = (float)v;
}

__global__ void k_gemm(const float* __restrict__ A, const float* __restrict__ Pin,
                       float* __restrict__ Pout, const float* __restrict__ tev, int div)
{
    int i = blockIdx.x, j = threadIdx.x;
    double h = (double)tev[1] - (double)tev[0];
    const float* Ar = A + i * NN;
    double acc = 0.0;
    for (int k = 0; k < NN; ++k) acc += (double)Ar[k] * (double)Pin[k * NN + j];
    double v = (i == j ? 1.0 : 0.0) + (h / (double)div) * acc;
    Pout[i * NN + j] = (float)v;
}

// gq = [g0 | g1 | g2 | g3 | q] — Round-2 proven
__global__ void k_prep_vec(const float* __restrict__ A, const float* __restrict__ B,
                           const float* __restrict__ cooling, const float* __restrict__ tev,
                           float* __restrict__ gq)
{
    __shared__ float heat[NN];
    __shared__ float vin[NN];
    int t = threadIdx.x;
    double h = (double)tev[1] - (double)tev[0];
    heat[t] = (t < NN - 2) ? 500.0f * sigm(cooling[t]) : 0.0f;
    __syncthreads();
    float B0 = B[t * (NN - 1)];
    double bh = 0.0;
    for (int j = 0; j < NN - 2; ++j) bh += (double)B[t * (NN - 1) + 1 + j] * (double)heat[j];
    vin[t] = B0; __syncthreads();
    double v1 = 0.0; for (int k = 0; k < NN; ++k) v1 += (double)A[t * NN + k] * (double)vin[k];
    __syncthreads(); vin[t] = (float)v1; __syncthreads();
    double v2 = 0.0; for (int k = 0; k < NN; ++k) v2 += (double)A[t * NN + k] * (double)vin[k];
    __syncthreads(); vin[t] = (float)v2; __syncthreads();
    double v3 = 0.0; for (int k = 0; k < NN; ++k) v3 += (double)A[t * NN + k] * (double)vin[k];
    __syncthreads();
    vin[t] = (float)bh; __syncthreads();
    double u1 = 0.0; for (int k = 0; k < NN; ++k) u1 += (double)A[t * NN + k] * (double)vin[k];
    __syncthreads(); vin[t] = (float)u1; __syncthreads();
    double u2 = 0.0; for (int k = 0; k < NN; ++k) u2 += (double)A[t * NN + k] * (double)vin[k];
    __syncthreads(); vin[t] = (float)u2; __syncthreads();
    double u3 = 0.0; for (int k = 0; k < NN; ++k) u3 += (double)A[t * NN + k] * (double)vin[k];

    gq[t]        = (float)((h / 6.0) * (double)B0);
    gq[256 + t]  = (float)((h * h / 6.0) * v1);
    gq[512 + t]  = (float)((h * h * h / 12.0) * v2);
    gq[768 + t]  = (float)((h * h * h * h / 24.0) * v3);
    gq[1024 + t] = (float)(h * bh + (h * h / 2.0) * u1 + (h * h * h / 6.0) * u2
                           + (h * h * h * h / 24.0) * u3);
}

__device__ __forceinline__ float interp1(float x, const float* __restrict__ ts,
                                         const float* __restrict__ vs, int n)
{
    int lo = 0, hi = n;
    while (lo < hi) { int mid = (lo + hi) >> 1; if (ts[mid] <= x) lo = mid + 1; else hi = mid; }
    int i = lo; if (i < 1) i = 1; if (i > n - 1) i = n - 1;
    float xim = ts[i - 1], xi = ts[i];
    float fim = vs[i - 1], fi = vs[i];
    return fim + (x - xim) / (xi - xim) * (fi - fim);
}

// td[k][0..7] = {S0,S1,S2,S3, sinD,cosD,sinW,cosW} — Round-2 proven
__global__ void k_time(const float* __restrict__ tev, const float* __restrict__ tts,
                       const float* __restrict__ tvals, float* __restrict__ td,
                       int T, int ntout)
{
    int k = blockIdx.x * blockDim.x + threadIdx.x;
    if (k >= T) return;
    float t0 = tev[0];
    float dtf = tev[1] - t0;
    float t = tev[k] - t0;
    const float cD = (float)(2.0 * M_PI / 86400.0);
    const float cW = (float)(2.0 * M_PI / 604800.0);
    float f0 = (float)sin((double)(t * cD));
    float f1 = (float)cos((double)(t * cD));
    float f2 = (float)sin((double)(t * cW));
    float f3 = (float)cos((double)(t * cW));
    float To1 = interp1(t + t0, tts, tvals, ntout);
    float To2 = interp1((t + 0.5f * dtf) + t0, tts, tvals, ntout);
    float To4 = interp1((t + dtf) + t0, tts, tvals, ntout);
    size_t o = (size_t)k * 8;
    td[o + 0] = To1 + 4.0f * To2 + To4;
    td[o + 1] = To1 + 2.0f * To2;
    td[o + 2] = To1 + To2;
    td[o + 3] = To1;
    td[o + 4] = f0; td[o + 5] = f1; td[o + 6] = f2; td[o + 7] = f3;
}

// Pack E = R - I as bf16 pairs (round-to-nearest-even), per-thread layout for k_main:
// Epk[t*32+i] = {bf16(E[r][seg*64+2i]) | bf16(E[r][seg*64+2i+1])<<16}, r=t&255, seg=t>>8.
__global__ void k_packE(const float* __restrict__ R, uint32* __restrict__ Epk)
{
    int d = blockIdx.x * 256 + threadIdx.x;   // 0..32767
    int t = d >> 5, i = d & 31;
    int r = t & 255, seg = t >> 8;
    int c = seg * 64 + 2 * i;
    float e0 = R[r * NN + c]     - (r == c     ? 1.0f : 0.0f);
    float e1 = R[r * NN + c + 1] - (r == c + 1 ? 1.0f : 0.0f);
    uint32 b0 = __float_as_uint(e0); b0 = (b0 + 0x7fffu + ((b0 >> 16) & 1u)) >> 16;
    uint32 b1 = __float_as_uint(e1); b1 = (b1 + 0x7fffu + ((b1 >> 16) & 1u)) >> 16;
    Epk[d] = b0 | (b1 << 16);
}

// ---------------- Sequential integrator ----------------
// 1 block, 1024 threads. E (bf16 pairs) in 32 VGPRs/thread; x fp32 in LDS
// (Round-2 broadcast-read path); policy weights fp32 in LDS (stride 276,
// bank-minimal). Register need ~55 < 64 cap.
__global__ __launch_bounds__(1024) void k_main(
    const float* __restrict__ tdata, const uint32* Epk,
    const float* __restrict__ gq, const float* __restrict__ w1g,
    const float* __restrict__ b1g, const float* __restrict__ w2g,
    float* out, int T)
{
    __shared__ __align__(16) float xbuf[NN];
    __shared__ __align__(16) float sbuf[NN];
    __shared__ __align__(16) float w1l[HH * W1STRIDE];
    __shared__ __align__(16) float part[4][NN];
    __shared__ float gql[5 * NN];
    __shared__ float wf[6 * HH];                 // w1f0..3, b1, w2
    __shared__ float hid[HH];
    __shared__ float b1eff[HH];
    __shared__ float td[2][8];

    const int t = threadIdx.x;
    const int r = t & 255;
    const int seg = t >> 8;      // quarter of the row
    const int jr = t >> 4;       // policy row 0..63
    const int c0 = t & 15;       // policy col chunk (16 cols)
    const int lane = t & 63;

    // E quarter-row -> 32 VGPRs (bf16 pairs)
    uint32 Ereg[32];
    {
        const uint4* Eg = reinterpret_cast<const uint4*>(Epk) + (size_t)t * 8;
        #pragma unroll
        for (int i = 0; i < 8; ++i) {
            uint4 v = Eg[i];
            Ereg[4 * i + 0] = v.x; Ereg[4 * i + 1] = v.y;
            Ereg[4 * i + 2] = v.z; Ereg[4 * i + 3] = v.w;
        }
    }
    // one-time LDS fills
    for (int i = t; i < HH * W1STRIDE; i += 1024) {
        int row = i / W1STRIDE, col = i - row * W1STRIDE;
        w1l[i] = (col < 256) ? w1g[row * 260 + col] : 0.0f;
    }
    for (int i = t; i < 5 * NN; i += 1024) gql[i] = gq[i];
    if (t < HH) {
        wf[t]       = w1g[t * 260 + 256];
        wf[64 + t]  = w1g[t * 260 + 257];
        wf[128 + t] = w1g[t * 260 + 258];
        wf[192 + t] = w1g[t * 260 + 259];
        wf[256 + t] = b1g[t];
        wf[320 + t] = w2g[t];
    }
    if (t < NN) { xbuf[t] = 26.0f; sbuf[t] = (26.0f - 23.359f) / 1.41f; }
    if (t < 8) td[0][t] = tdata[t];
    __syncthreads();
    if (t < HH)
        b1eff[t] = wf[256 + t] + wf[t] * td[0][4] + wf[64 + t] * td[0][5]
                 + wf[128 + t] * td[0][6] + wf[192 + t] * td[0][7];
    __syncthreads();

    for (int k = 0; k < T; ++k) {
        const int cur = k & 1, nxt = cur ^ 1;
        float tdp = 0.0f;
        if (t >= 1016 && k + 1 < T) tdp = tdata[(size_t)(k + 1) * 8 + (t - 1016)];

        // ---- Phase A: policy hidden + matvec partials + out write ----
        float hs = 0.0f;
        {
            const float4* wb = reinterpret_cast<const float4*>(w1l + jr * W1STRIDE + c0 * 16);
            const float4* sb = reinterpret_cast<const float4*>(sbuf + c0 * 16);
            #pragma unroll
            for (int i = 0; i < 4; ++i) {
                float4 w = wb[i]; float4 s = sb[i];
                hs += w.x * s.x + w.y * s.y + w.z * s.z + w.w * s.w;
            }
        }
        hs += __shfl_xor(hs, 1); hs += __shfl_xor(hs, 2);
        hs += __shfl_xor(hs, 4); hs += __shfl_xor(hs, 8);
        if (c0 == 0) hid[jr] = tanhf(hs + b1eff[jr]);

        float a0 = 0.f, a1 = 0.f, a2 = 0.f, a3 = 0.f;
        {
            const float4* xb4 = reinterpret_cast<const float4*>(xbuf) + seg * 16;
            #pragma unroll
            for (int f = 0; f < 16; ++f) {
                float4 xv = xb4[f];
                uint32 u0 = Ereg[2 * f], u1 = Ereg[2 * f + 1];
                a0 += __uint_as_float(u0 << 16)          * xv.x;
                a1 += __uint_as_float(u0 & 0xffff0000u)  * xv.y;
                a2 += __uint_as_float(u1 << 16)          * xv.z;
                a3 += __uint_as_float(u1 & 0xffff0000u)  * xv.w;
            }
        }
        part[seg][r] = (a0 + a1) + (a2 + a3);
        if (t < NN) out[(size_t)k * NN + t] = xbuf[t];
        if (t >= 1016) td[nxt][t - 1016] = tdp;
        asm volatile("s_waitcnt lgkmcnt(0)\ns_barrier" ::: "memory");

        // ---- Phase B: action + combine ----
        if (t < NN) {
            float v = wf[320 + lane] * hid[lane];
            v += __shfl_xor(v, 1);  v += __shfl_xor(v, 2);  v += __shfl_xor(v, 4);
            v += __shfl_xor(v, 8);  v += __shfl_xor(v, 16); v += __shfl_xor(v, 32);
            float aS = sigm(v);
            float S0 = td[cur][0], S1 = td[cur][1], S2 = td[cur][2], S3 = td[cur][3];
            float y = (part[0][t] + part[1][t]) + (part[2][t] + part[3][t]);
            float xn = xbuf[t] + y + S0 * gql[t] + S1 * gql[256 + t] + S2 * gql[512 + t]
                     + S3 * gql[768 + t] - aS * gql[1024 + t];
            xbuf[t] = xn;
            sbuf[t] = (xn - 23.359f) / 1.41f;
        } else if (t >= 512 && t < 576 && k + 1 < T) {
            int j = t - 512;
            b1eff[j] = wf[256 + j] + wf[j] * td[nxt][4] + wf[64 + j] * td[nxt][5]
                     + wf[128 + j] * td[nxt][6] + wf[192 + j] * td[nxt][7];
        }
        asm volatile("s_waitcnt lgkmcnt(0)\ns_barrier" ::: "memory");
    }
}

extern "C" void kernel_launch(void* const* d_in, const int* in_sizes, int n_in,
                              void* d_out, int out_size, void* d_ws, size_t ws_size,
                              hipStream_t stream)
{
    (void)n_in; (void)out_size; (void)ws_size;
    const float* tev     = (const float*)d_in[0];
    const float* A       = (const float*)d_in[1];
    const float* B       = (const float*)d_in[2];
    const float* cooling = (const float*)d_in[3];
    const float* w1      = (const float*)d_in[4];
    const float* b1      = (const float*)d_in[5];
    const float* w2      = (const float*)d_in[6];
    const float* tts     = (const float*)d_in[7];
    const float* tvals   = (const float*)d_in[8];
    const int T     = in_sizes[0];
    const int ntout = in_sizes[7];

    float* out = (float*)d_out;
    float* ws  = (float*)d_ws;
    float* R   = ws;                       // 65536 floats
    float* gq  = ws + 65536;               // 1280 floats
    float* td  = ws + 65536 + 1280;        // T*8 floats
    float* P1  = out;                      // GEMM ping-pong (rewritten by k_main)
    float* P2  = out + 65536;
    // packed E in the out tail (read once at k_main start; those out positions
    // are rewritten by k_main's final trajectory steps afterwards)
    size_t outN = (size_t)T * NN;
    uint32* Epk = (uint32*)(out + outN - 32768);            // 128 KB

    hipLaunchKernelGGL(k_affine, dim3(256), dim3(256), 0, stream, A, P1, tev, 4);
    hipLaunchKernelGGL(k_gemm,   dim3(256), dim3(256), 0, stream, A, P1, P2, tev, 3);
    hipLaunchKernelGGL(k_gemm,   dim3(256), dim3(256), 0, stream, A, P2, P1, tev, 2);
    hipLaunchKernelGGL(k_gemm,   dim3(256), dim3(256), 0, stream, A, P1, R,  tev, 1);
    hipLaunchKernelGGL(k_packE,  dim3(128), dim3(256), 0, stream, R, Epk);
    hipLaunchKernelGGL(k_prep_vec, dim3(1), dim3(256), 0, stream, A, B, cooling, tev, gq);
    hipLaunchKernelGGL(k_time, dim3((T + 255) / 256), dim3(256), 0, stream,
                       tev, tts, tvals, td, T, ntout);
    hipLaunchKernelGGL(k_main, dim3(1), dim3(1024), 0, stream,
                       td, Epk, gq, w1, b1, w2, out, T);
}

// Round 5
// 60557.581 us; speedup vs baseline: 7.1829x; 1.6730x over previous
//
#include <hip/hip_runtime.h>
#include <math.h>

#define NN 256
#define HH 64

typedef unsigned int uint32;
typedef _Float16 h2f __attribute__((ext_vector_type(2)));

__device__ __forceinline__ float sigm(float x) { return 1.0f / (1.0f + expf(-x)); }

// 2 f16 MACs, f32 accumulate
__device__ __forceinline__ float dot2(uint32 a, uint32 b, float c) {
#if __has_builtin(__builtin_amdgcn_fdot2)
    return __builtin_amdgcn_fdot2(__builtin_bit_cast(h2f, a),
                                  __builtin_bit_cast(h2f, b), c, false);
#else
    h2f x = __builtin_bit_cast(h2f, a), y = __builtin_bit_cast(h2f, b);
    return c + (float)x[0] * (float)y[0] + (float)x[1] * (float)y[1];
#endif
}

// ---------------- R construction (fp64 GEMM chain) — proven ----------------
__global__ void k_affine(const float* __restrict__ A, float* __restrict__ Pout,
                         const float* __restrict__ tev, int div)
{
    int i = blockIdx.x, j = threadIdx.x;
    double h = (double)tev[1] - (double)tev[0];
    double v = (i == j ? 1.0 : 0.0) + (h / (double)div) * (double)A[i * NN + j];
    Pout[i * NN + j] = (float)v;
}

__global__ void k_gemm(const float* __restrict__ A, const float* __restrict__ Pin,
                       float* __restrict__ Pout, const float* __restrict__ tev, int div)
{
    int i = blockIdx.x, j = threadIdx.x;
    double h = (double)tev[1] - (double)tev[0];
    const float* Ar = A + i * NN;
    double acc = 0.0;
    for (int k = 0; k < NN; ++k) acc += (double)Ar[k] * (double)Pin[k * NN + j];
    double v = (i == j ? 1.0 : 0.0) + (h / (double)div) * acc;
    Pout[i * NN + j] = (float)v;
}

// gq = [g0 | g1 | g2 | g3 | q | ce]  (ce = MU * rowsum(R - I), fp64)
__global__ void k_prep_vec(const float* __restrict__ A, const float* __restrict__ B,
                           const float* __restrict__ cooling, const float* __restrict__ tev,
                           const float* __restrict__ R, float* __restrict__ gq)
{
    __shared__ float heat[NN];
    __shared__ float vin[NN];
    int t = threadIdx.x;
    double h = (double)tev[1] - (double)tev[0];
    heat[t] = (t < NN - 2) ? 500.0f * sigm(cooling[t]) : 0.0f;
    __syncthreads();
    float B0 = B[t * (NN - 1)];
    double bh = 0.0;
    for (int j = 0; j < NN - 2; ++j) bh += (double)B[t * (NN - 1) + 1 + j] * (double)heat[j];
    vin[t] = B0; __syncthreads();
    double v1 = 0.0; for (int k = 0; k < NN; ++k) v1 += (double)A[t * NN + k] * (double)vin[k];
    __syncthreads(); vin[t] = (float)v1; __syncthreads();
    double v2 = 0.0; for (int k = 0; k < NN; ++k) v2 += (double)A[t * NN + k] * (double)vin[k];
    __syncthreads(); vin[t] = (float)v2; __syncthreads();
    double v3 = 0.0; for (int k = 0; k < NN; ++k) v3 += (double)A[t * NN + k] * (double)vin[k];
    __syncthreads();
    vin[t] = (float)bh; __syncthreads();
    double u1 = 0.0; for (int k = 0; k < NN; ++k) u1 += (double)A[t * NN + k] * (double)vin[k];
    __syncthreads(); vin[t] = (float)u1; __syncthreads();
    double u2 = 0.0; for (int k = 0; k < NN; ++k) u2 += (double)A[t * NN + k] * (double)vin[k];
    __syncthreads(); vin[t] = (float)u2; __syncthreads();
    double u3 = 0.0; for (int k = 0; k < NN; ++k) u3 += (double)A[t * NN + k] * (double)vin[k];

    double srow = 0.0;
    for (int c = 0; c < NN; ++c) srow += (double)R[t * NN + c];
    srow -= 1.0;                               // rowsum(E)

    gq[t]        = (float)((h / 6.0) * (double)B0);
    gq[256 + t]  = (float)((h * h / 6.0) * v1);
    gq[512 + t]  = (float)((h * h * h / 12.0) * v2);
    gq[768 + t]  = (float)((h * h * h * h / 24.0) * v3);
    gq[1024 + t] = (float)(h * bh + (h * h / 2.0) * u1 + (h * h * h / 6.0) * u2
                           + (h * h * h * h / 24.0) * u3);
    gq[1280 + t] = (float)(23.359 * srow);
}

__device__ __forceinline__ float interp1(float x, const float* __restrict__ ts,
                                         const float* __restrict__ vs, int n)
{
    int lo = 0, hi = n;
    while (lo < hi) { int mid = (lo + hi) >> 1; if (ts[mid] <= x) lo = mid + 1; else hi = mid; }
    int i = lo; if (i < 1) i = 1; if (i > n - 1) i = n - 1;
    float xim = ts[i - 1], xi = ts[i];
    float fim = vs[i - 1], fi = vs[i];
    return fim + (x - xim) / (xi - xim) * (fi - fim);
}

// td[k][0..7] = {S0,S1,S2,S3, sinD,cosD,sinW,cosW} — proven
__global__ void k_time(const float* __restrict__ tev, const float* __restrict__ tts,
                       const float* __restrict__ tvals, float* __restrict__ td,
                       int T, int ntout)
{
    int k = blockIdx.x * blockDim.x + threadIdx.x;
    if (k >= T) return;
    float t0 = tev[0];
    float dtf = tev[1] - t0;
    float t = tev[k] - t0;
    const float cD = (float)(2.0 * M_PI / 86400.0);
    const float cW = (float)(2.0 * M_PI / 604800.0);
    float f0 = (float)sin((double)(t * cD));
    float f1 = (float)cos((double)(t * cD));
    float f2 = (float)sin((double)(t * cW));
    float f3 = (float)cos((double)(t * cW));
    float To1 = interp1(t + t0, tts, tvals, ntout);
    float To2 = interp1((t + 0.5f * dtf) + t0, tts, tvals, ntout);
    float To4 = interp1((t + dtf) + t0, tts, tvals, ntout);
    size_t o = (size_t)k * 8;
    td[o + 0] = To1 + 4.0f * To2 + To4;
    td[o + 1] = To1 + 2.0f * To2;
    td[o + 2] = To1 + To2;
    td[o + 3] = To1;
    td[o + 4] = f0; td[o + 5] = f1; td[o + 6] = f2; td[o + 7] = f3;
}

// Pack E = 64*(R - I) as f16 pairs, per-thread layout for 512-thread k_main:
// thread t (r=t&255, hf=t>>8) owns cols hf*128..hf*128+127 of row r as 64 dwords.
__global__ void k_packE(const float* __restrict__ R, uint32* __restrict__ Epk)
{
    int d = blockIdx.x * 256 + threadIdx.x;   // 0..32767
    int t = d >> 6, i = d & 63;
    int r = t & 255, hf = t >> 8;
    int c = hf * 128 + 2 * i;
    float e0 = 64.0f * (R[r * NN + c]     - (r == c     ? 1.0f : 0.0f));
    float e1 = 64.0f * (R[r * NN + c + 1] - (r == c + 1 ? 1.0f : 0.0f));
    union { _Float16 h[2]; uint32 u; } p;
    p.h[0] = (_Float16)e0; p.h[1] = (_Float16)e1;
    Epk[d] = p.u;
}

// Pack w1 state-cols / 1.41 as f16 pairs. Thread slot t=(jr*8+c) owns 16 dwords:
// slot j (0..7): dwords 2j,2j+1 = cols {c*4+j*32 .. +3}.
__global__ void k_packW(const float* __restrict__ w1, uint32* __restrict__ w1pk)
{
    int d = blockIdx.x * 256 + threadIdx.x;   // 0..8191
    int t = d >> 4, sd = d & 15;
    int jr = t >> 3, c = t & 7;
    int j = sd >> 1, p = sd & 1;
    int col = c * 4 + j * 32 + 2 * p;
    const float is = 1.0f / 1.41f;
    union { _Float16 h[2]; uint32 u; } q;
    q.h[0] = (_Float16)(w1[jr * 260 + col] * is);
    q.h[1] = (_Float16)(w1[jr * 260 + col + 1] * is);
    w1pk[d] = q.u;
}

// ---------------- Sequential integrator ----------------
// 512 threads (8 waves, 128-VGPR cap). E f16x64 in 64 VGPRs, w1 f16 in 16 VGPRs.
// State: x' = x - MU as f16 pairs in LDS (broadcast reads), x fp32 for output.
__global__ __launch_bounds__(512, 2) void k_main(
    const float* __restrict__ tdata, const uint32* Epk,
    const uint32* __restrict__ w1pk, const float* __restrict__ gq,
    const float* __restrict__ w1g, const float* __restrict__ b1g,
    const float* __restrict__ w2g, float* out, int T)
{
    __shared__ __align__(16) uint32 spk[132];     // x' f16 pairs (128 used)
    __shared__ __align__(16) float xbuf[NN];
    __shared__ __align__(16) float part[2][NN];
    __shared__ float gql[6 * NN];
    __shared__ float wf[6 * HH];                  // w1f0..3, b1, w2
    __shared__ float hid[HH];
    __shared__ float b1eff[HH];
    __shared__ float td[2][8];

    const int t = threadIdx.x;
    const int r = t & 255;
    const int hf = t >> 8;        // half of the row
    const int jr = t >> 3;        // policy row 0..63
    const int c2 = (t & 7) * 2;   // policy dword base
    const int lane = t & 63;

    // E half-row -> 64 VGPRs (f16 pairs, x64)
    uint32 Ereg[64];
    {
        const uint4* Eg = reinterpret_cast<const uint4*>(Epk) + (size_t)t * 16;
        #pragma unroll
        for (int i = 0; i < 16; ++i) {
            uint4 v = Eg[i];
            Ereg[4 * i + 0] = v.x; Ereg[4 * i + 1] = v.y;
            Ereg[4 * i + 2] = v.z; Ereg[4 * i + 3] = v.w;
        }
    }
    // policy chunk -> 16 VGPRs
    uint32 w1reg[16];
    {
        const uint4* Wg = reinterpret_cast<const uint4*>(w1pk) + (size_t)t * 4;
        #pragma unroll
        for (int i = 0; i < 4; ++i) {
            uint4 v = Wg[i];
            w1reg[4 * i + 0] = v.x; w1reg[4 * i + 1] = v.y;
            w1reg[4 * i + 2] = v.z; w1reg[4 * i + 3] = v.w;
        }
    }
    for (int i = t; i < 6 * NN; i += 512) gql[i] = gq[i];
    if (t < HH) {
        wf[t]       = w1g[t * 260 + 256];
        wf[64 + t]  = w1g[t * 260 + 257];
        wf[128 + t] = w1g[t * 260 + 258];
        wf[192 + t] = w1g[t * 260 + 259];
        wf[256 + t] = b1g[t];
        wf[320 + t] = w2g[t];
    }
    _Float16* sph = reinterpret_cast<_Float16*>(spk);
    if (t < NN) {
        xbuf[t] = 26.0f;
        sph[t] = (_Float16)(26.0f - 23.359f);
    }
    if (t < 8) td[0][t] = tdata[t];
    __syncthreads();
    if (t < HH)
        b1eff[t] = wf[256 + t] + wf[t] * td[0][4] + wf[64 + t] * td[0][5]
                 + wf[128 + t] * td[0][6] + wf[192 + t] * td[0][7];
    __syncthreads();

    const uint4* sp4 = reinterpret_cast<const uint4*>(spk);

    for (int k = 0; k < T; ++k) {
        const int cur = k & 1, nxt = cur ^ 1;
        float tdp = 0.0f;
        if (t >= 504 && k + 1 < T) tdp = tdata[(size_t)(k + 1) * 8 + (t - 504)];

        // ---- Phase A ----
        // policy hidden: hs = (w1/1.41) . x'  (8 conflict-free b64 broadcasts)
        float hs = 0.0f;
        {
            #pragma unroll
            for (int j = 0; j < 8; ++j) {
                uint2 sx = *reinterpret_cast<const uint2*>(spk + c2 + j * 16);
                hs = dot2(w1reg[2 * j], sx.x, hs);
                hs = dot2(w1reg[2 * j + 1], sx.y, hs);
            }
        }
        hs += __shfl_xor(hs, 1); hs += __shfl_xor(hs, 2); hs += __shfl_xor(hs, 4);
        if ((t & 7) == 0) hid[jr] = tanhf(hs + b1eff[jr]);

        // E-matvec half-row: 64 dot2 on broadcast x' (4 chunks, capped liveness)
        float ac0 = 0.f, ac1 = 0.f, ac2 = 0.f, ac3 = 0.f;
        const uint4* xp = sp4 + hf * 16;
        #define ECHUNK(B) { \
            uint4 q0 = xp[(B) + 0], q1 = xp[(B) + 1], q2 = xp[(B) + 2], q3 = xp[(B) + 3]; \
            ac0 = dot2(Ereg[4*(B)+ 0], q0.x, ac0); ac1 = dot2(Ereg[4*(B)+ 1], q0.y, ac1); \
            ac2 = dot2(Ereg[4*(B)+ 2], q0.z, ac2); ac3 = dot2(Ereg[4*(B)+ 3], q0.w, ac3); \
            ac0 = dot2(Ereg[4*(B)+ 4], q1.x, ac0); ac1 = dot2(Ereg[4*(B)+ 5], q1.y, ac1); \
            ac2 = dot2(Ereg[4*(B)+ 6], q1.z, ac2); ac3 = dot2(Ereg[4*(B)+ 7], q1.w, ac3); \
            ac0 = dot2(Ereg[4*(B)+ 8], q2.x, ac0); ac1 = dot2(Ereg[4*(B)+ 9], q2.y, ac1); \
            ac2 = dot2(Ereg[4*(B)+10], q2.z, ac2); ac3 = dot2(Ereg[4*(B)+11], q2.w, ac3); \
            ac0 = dot2(Ereg[4*(B)+12], q3.x, ac0); ac1 = dot2(Ereg[4*(B)+13], q3.y, ac1); \
            ac2 = dot2(Ereg[4*(B)+14], q3.z, ac2); ac3 = dot2(Ereg[4*(B)+15], q3.w, ac3); }
        ECHUNK(0)
        __builtin_amdgcn_sched_barrier(0);
        ECHUNK(4)
        __builtin_amdgcn_sched_barrier(0);
        ECHUNK(8)
        __builtin_amdgcn_sched_barrier(0);
        ECHUNK(12)
        #undef ECHUNK
        part[hf][r] = (ac0 + ac1) + (ac2 + ac3);

        if (t < NN) out[(size_t)k * NN + t] = xbuf[t];
        if (t >= 504) td[nxt][t - 504] = tdp;
        asm volatile("s_waitcnt lgkmcnt(0)\ns_barrier" ::: "memory");

        // ---- Phase B ----
        if (t < NN) {
            float v = wf[320 + lane] * hid[lane];
            v += __shfl_xor(v, 1);  v += __shfl_xor(v, 2);  v += __shfl_xor(v, 4);
            v += __shfl_xor(v, 8);  v += __shfl_xor(v, 16); v += __shfl_xor(v, 32);
            float aS = sigm(v);
            float S0 = td[cur][0], S1 = td[cur][1], S2 = td[cur][2], S3 = td[cur][3];
            float y = (part[0][t] + part[1][t]) * 0.015625f;   // /64 scale
            float xn = xbuf[t] + y + gql[1280 + t]
                     + S0 * gql[t] + S1 * gql[256 + t] + S2 * gql[512 + t]
                     + S3 * gql[768 + t] - aS * gql[1024 + t];
            xbuf[t] = xn;
            sph[t] = (_Float16)(xn - 23.359f);
        } else if (t < 320 && k + 1 < T) {
            int j = t - 256;
            b1eff[j] = wf[256 + j] + wf[j] * td[nxt][4] + wf[64 + j] * td[nxt][5]
                     + wf[128 + j] * td[nxt][6] + wf[192 + j] * td[nxt][7];
        }
        asm volatile("s_waitcnt lgkmcnt(0)\ns_barrier" ::: "memory");
    }
}

extern "C" void kernel_launch(void* const* d_in, const int* in_sizes, int n_in,
                              void* d_out, int out_size, void* d_ws, size_t ws_size,
                              hipStream_t stream)
{
    (void)n_in; (void)out_size; (void)ws_size;
    const float* tev     = (const float*)d_in[0];
    const float* A       = (const float*)d_in[1];
    const float* B       = (const float*)d_in[2];
    const float* cooling = (const float*)d_in[3];
    const float* w1      = (const float*)d_in[4];
    const float* b1      = (const float*)d_in[5];
    const float* w2      = (const float*)d_in[6];
    const float* tts     = (const float*)d_in[7];
    const float* tvals   = (const float*)d_in[8];
    const int T     = in_sizes[0];
    const int ntout = in_sizes[7];

    float* out = (float*)d_out;
    float* ws  = (float*)d_ws;
    float*  R    = ws;                          // 65536 floats
    float*  gq   = ws + 65536;                  // 1536 floats
    uint32* w1pk = (uint32*)(ws + 67072);       // 8192 dwords
    float*  td   = ws + 75264;                  // T*8 floats
    float* P1 = out;                            // GEMM ping-pong (rewritten by k_main)
    float* P2 = out + 65536;
    size_t outN = (size_t)T * NN;
    uint32* Epk = (uint32*)(out + outN - 32768);  // 128 KB tail, read before overwritten

    hipLaunchKernelGGL(k_affine, dim3(256), dim3(256), 0, stream, A, P1, tev, 4);
    hipLaunchKernelGGL(k_gemm,   dim3(256), dim3(256), 0, stream, A, P1, P2, tev, 3);
    hipLaunchKernelGGL(k_gemm,   dim3(256), dim3(256), 0, stream, A, P2, P1, tev, 2);
    hipLaunchKernelGGL(k_gemm,   dim3(256), dim3(256), 0, stream, A, P1, R,  tev, 1);
    hipLaunchKernelGGL(k_packE,  dim3(128), dim3(256), 0, stream, R, Epk);
    hipLaunchKernelGGL(k_packW,  dim3(32),  dim3(256), 0, stream, w1, w1pk);
    hipLaunchKernelGGL(k_prep_vec, dim3(1), dim3(256), 0, stream, A, B, cooling, tev, R, gq);
    hipLaunchKernelGGL(k_time, dim3((T + 255) / 256), dim3(256), 0, stream,
                       tev, tts, tvals, td, T, ntout);
    hipLaunchKernelGGL(k_main, dim3(1), dim3(512), 0, stream,
                       td, Epk, w1pk, gq, w1, b1, w2, out, T);
}

// Round 6
// 57166.223 us; speedup vs baseline: 7.6090x; 1.0593x over previous
//
#include <hip/hip_runtime.h>
#include <math.h>

#define NN 256
#define HH 64

typedef unsigned int uint32;
typedef _Float16 h2f __attribute__((ext_vector_type(2)));

__device__ __forceinline__ float sigm(float x) { return 1.0f / (1.0f + expf(-x)); }

// 2 f16 MACs, f32 accumulate
__device__ __forceinline__ float dot2(uint32 a, uint32 b, float c) {
#if __has_builtin(__builtin_amdgcn_fdot2)
    return __builtin_amdgcn_fdot2(__builtin_bit_cast(h2f, a),
                                  __builtin_bit_cast(h2f, b), c, false);
#else
    h2f x = __builtin_bit_cast(h2f, a), y = __builtin_bit_cast(h2f, b);
    return c + (float)x[0] * (float)y[0] + (float)x[1] * (float)y[1];
#endif
}

// ---------------- R construction (fp64 GEMM chain) — proven ----------------
__global__ void k_affine(const float* __restrict__ A, float* __restrict__ Pout,
                         const float* __restrict__ tev, int div)
{
    int i = blockIdx.x, j = threadIdx.x;
    double h = (double)tev[1] - (double)tev[0];
    double v = (i == j ? 1.0 : 0.0) + (h / (double)div) * (double)A[i * NN + j];
    Pout[i * NN + j] = (float)v;
}

__global__ void k_gemm(const float* __restrict__ A, const float* __restrict__ Pin,
                       float* __restrict__ Pout, const float* __restrict__ tev, int div)
{
    int i = blockIdx.x, j = threadIdx.x;
    double h = (double)tev[1] - (double)tev[0];
    const float* Ar = A + i * NN;
    double acc = 0.0;
    for (int k = 0; k < NN; ++k) acc += (double)Ar[k] * (double)Pin[k * NN + j];
    double v = (i == j ? 1.0 : 0.0) + (h / (double)div) * acc;
    Pout[i * NN + j] = (float)v;
}

// gq = [g0 | g1 | g2 | g3 | q | ce]  (ce = MU * rowsum(R - I), fp64) — proven
__global__ void k_prep_vec(const float* __restrict__ A, const float* __restrict__ B,
                           const float* __restrict__ cooling, const float* __restrict__ tev,
                           const float* __restrict__ R, float* __restrict__ gq)
{
    __shared__ float heat[NN];
    __shared__ float vin[NN];
    int t = threadIdx.x;
    double h = (double)tev[1] - (double)tev[0];
    heat[t] = (t < NN - 2) ? 500.0f * sigm(cooling[t]) : 0.0f;
    __syncthreads();
    float B0 = B[t * (NN - 1)];
    double bh = 0.0;
    for (int j = 0; j < NN - 2; ++j) bh += (double)B[t * (NN - 1) + 1 + j] * (double)heat[j];
    vin[t] = B0; __syncthreads();
    double v1 = 0.0; for (int k = 0; k < NN; ++k) v1 += (double)A[t * NN + k] * (double)vin[k];
    __syncthreads(); vin[t] = (float)v1; __syncthreads();
    double v2 = 0.0; for (int k = 0; k < NN; ++k) v2 += (double)A[t * NN + k] * (double)vin[k];
    __syncthreads(); vin[t] = (float)v2; __syncthreads();
    double v3 = 0.0; for (int k = 0; k < NN; ++k) v3 += (double)A[t * NN + k] * (double)vin[k];
    __syncthreads();
    vin[t] = (float)bh; __syncthreads();
    double u1 = 0.0; for (int k = 0; k < NN; ++k) u1 += (double)A[t * NN + k] * (double)vin[k];
    __syncthreads(); vin[t] = (float)u1; __syncthreads();
    double u2 = 0.0; for (int k = 0; k < NN; ++k) u2 += (double)A[t * NN + k] * (double)vin[k];
    __syncthreads(); vin[t] = (float)u2; __syncthreads();
    double u3 = 0.0; for (int k = 0; k < NN; ++k) u3 += (double)A[t * NN + k] * (double)vin[k];

    double srow = 0.0;
    for (int c = 0; c < NN; ++c) srow += (double)R[t * NN + c];
    srow -= 1.0;                               // rowsum(E)

    gq[t]        = (float)((h / 6.0) * (double)B0);
    gq[256 + t]  = (float)((h * h / 6.0) * v1);
    gq[512 + t]  = (float)((h * h * h / 12.0) * v2);
    gq[768 + t]  = (float)((h * h * h * h / 24.0) * v3);
    gq[1024 + t] = (float)(h * bh + (h * h / 2.0) * u1 + (h * h * h / 6.0) * u2
                           + (h * h * h * h / 24.0) * u3);
    gq[1280 + t] = (float)(23.359 * srow);
}

__device__ __forceinline__ float interp1(float x, const float* __restrict__ ts,
                                         const float* __restrict__ vs, int n)
{
    int lo = 0, hi = n;
    while (lo < hi) { int mid = (lo + hi) >> 1; if (ts[mid] <= x) lo = mid + 1; else hi = mid; }
    int i = lo; if (i < 1) i = 1; if (i > n - 1) i = n - 1;
    float xim = ts[i - 1], xi = ts[i];
    float fim = vs[i - 1], fi = vs[i];
    return fim + (x - xim) / (xi - xim) * (fi - fim);
}

// td[k][0..7] = {S0,S1,S2,S3, sinD,cosD,sinW,cosW} — proven
__global__ void k_time(const float* __restrict__ tev, const float* __restrict__ tts,
                       const float* __restrict__ tvals, float* __restrict__ td,
                       int T, int ntout)
{
    int k = blockIdx.x * blockDim.x + threadIdx.x;
    if (k >= T) return;
    float t0 = tev[0];
    float dtf = tev[1] - t0;
    float t = tev[k] - t0;
    const float cD = (float)(2.0 * M_PI / 86400.0);
    const float cW = (float)(2.0 * M_PI / 604800.0);
    float f0 = (float)sin((double)(t * cD));
    float f1 = (float)cos((double)(t * cD));
    float f2 = (float)sin((double)(t * cW));
    float f3 = (float)cos((double)(t * cW));
    float To1 = interp1(t + t0, tts, tvals, ntout);
    float To2 = interp1((t + 0.5f * dtf) + t0, tts, tvals, ntout);
    float To4 = interp1((t + dtf) + t0, tts, tvals, ntout);
    size_t o = (size_t)k * 8;
    td[o + 0] = To1 + 4.0f * To2 + To4;
    td[o + 1] = To1 + 2.0f * To2;
    td[o + 2] = To1 + To2;
    td[o + 3] = To1;
    td[o + 4] = f0; td[o + 5] = f1; td[o + 6] = f2; td[o + 7] = f3;
}

// Pack E = 64*(R - I) as f16 pairs — layout proven in R5.
__global__ void k_packE(const float* __restrict__ R, uint32* __restrict__ Epk)
{
    int d = blockIdx.x * 256 + threadIdx.x;   // 0..32767
    int t = d >> 6, i = d & 63;
    int r = t & 255, hf = t >> 8;
    int c = hf * 128 + 2 * i;
    float e0 = 64.0f * (R[r * NN + c]     - (r == c     ? 1.0f : 0.0f));
    float e1 = 64.0f * (R[r * NN + c + 1] - (r == c + 1 ? 1.0f : 0.0f));
    union { _Float16 h[2]; uint32 u; } p;
    p.h[0] = (_Float16)e0; p.h[1] = (_Float16)e1;
    Epk[d] = p.u;
}

// Pack w1 state-cols / 1.41 as f16 pairs — layout proven in R5.
__global__ void k_packW(const float* __restrict__ w1, uint32* __restrict__ w1pk)
{
    int d = blockIdx.x * 256 + threadIdx.x;   // 0..8191
    int t = d >> 4, sd = d & 15;
    int jr = t >> 3, c = t & 7;
    int j = sd >> 1, p = sd & 1;
    int col = c * 4 + j * 32 + 2 * p;
    const float is = 1.0f / 1.41f;
    union { _Float16 h[2]; uint32 u; } q;
    q.h[0] = (_Float16)(w1[jr * 260 + col] * is);
    q.h[1] = (_Float16)(w1[jr * 260 + col + 1] * is);
    w1pk[d] = q.u;
}

// ---------------- Sequential integrator ----------------
// 512 threads (8 waves). E half-row in 64 NAMED scalar uint32 (SSA from birth,
// no alloca/SROA involved); w1 chunk in 16 named scalars. No launch_bounds
// arg2, no sched_barriers — maximize allocator freedom.
__global__ __launch_bounds__(512) void k_main(
    const float* __restrict__ tdata, const uint32* Epk,
    const uint32* __restrict__ w1pk, const float* __restrict__ gq,
    const float* __restrict__ w1g, const float* __restrict__ b1g,
    const float* __restrict__ w2g, float* out, int T)
{
    __shared__ __align__(16) uint32 spk[132];     // x' f16 pairs (128 used)
    __shared__ __align__(16) float xbuf[NN];
    __shared__ __align__(16) float part[2][NN];
    __shared__ float gql[6 * NN];
    __shared__ float wf[6 * HH];                  // w1f0..3, b1, w2
    __shared__ float hid[HH];
    __shared__ float b1eff[HH];
    __shared__ float td[2][8];

    const int t = threadIdx.x;
    const int r = t & 255;
    const int hf = t >> 8;        // half of the row
    const int jr = t >> 3;        // policy row 0..63
    const int c2 = (t & 7) * 2;   // policy dword base
    const int lane = t & 63;

    // E half-row -> 64 named VGPR values (f16 pairs, x64 scale)
    uint32 e0,e1,e2,e3,e4,e5,e6,e7,e8,e9,e10,e11,e12,e13,e14,e15,
           e16,e17,e18,e19,e20,e21,e22,e23,e24,e25,e26,e27,e28,e29,e30,e31,
           e32,e33,e34,e35,e36,e37,e38,e39,e40,e41,e42,e43,e44,e45,e46,e47,
           e48,e49,e50,e51,e52,e53,e54,e55,e56,e57,e58,e59,e60,e61,e62,e63;
    {
        const uint4* Eg = reinterpret_cast<const uint4*>(Epk) + (size_t)t * 16;
        uint4 v;
        v = Eg[0];  e0  = v.x; e1  = v.y; e2  = v.z; e3  = v.w;
        v = Eg[1];  e4  = v.x; e5  = v.y; e6  = v.z; e7  = v.w;
        v = Eg[2];  e8  = v.x; e9  = v.y; e10 = v.z; e11 = v.w;
        v = Eg[3];  e12 = v.x; e13 = v.y; e14 = v.z; e15 = v.w;
        v = Eg[4];  e16 = v.x; e17 = v.y; e18 = v.z; e19 = v.w;
        v = Eg[5];  e20 = v.x; e21 = v.y; e22 = v.z; e23 = v.w;
        v = Eg[6];  e24 = v.x; e25 = v.y; e26 = v.z; e27 = v.w;
        v = Eg[7];  e28 = v.x; e29 = v.y; e30 = v.z; e31 = v.w;
        v = Eg[8];  e32 = v.x; e33 = v.y; e34 = v.z; e35 = v.w;
        v = Eg[9];  e36 = v.x; e37 = v.y; e38 = v.z; e39 = v.w;
        v = Eg[10]; e40 = v.x; e41 = v.y; e42 = v.z; e43 = v.w;
        v = Eg[11]; e44 = v.x; e45 = v.y; e46 = v.z; e47 = v.w;
        v = Eg[12]; e48 = v.x; e49 = v.y; e50 = v.z; e51 = v.w;
        v = Eg[13]; e52 = v.x; e53 = v.y; e54 = v.z; e55 = v.w;
        v = Eg[14]; e56 = v.x; e57 = v.y; e58 = v.z; e59 = v.w;
        v = Eg[15]; e60 = v.x; e61 = v.y; e62 = v.z; e63 = v.w;
    }
    // policy chunk -> 16 named values
    uint32 p0,p1,p2,p3,p4,p5,p6,p7,p8,p9,p10,p11,p12,p13,p14,p15;
    {
        const uint4* Wg = reinterpret_cast<const uint4*>(w1pk) + (size_t)t * 4;
        uint4 v;
        v = Wg[0]; p0  = v.x; p1  = v.y; p2  = v.z; p3  = v.w;
        v = Wg[1]; p4  = v.x; p5  = v.y; p6  = v.z; p7  = v.w;
        v = Wg[2]; p8  = v.x; p9  = v.y; p10 = v.z; p11 = v.w;
        v = Wg[3]; p12 = v.x; p13 = v.y; p14 = v.z; p15 = v.w;
    }
    for (int i = t; i < 6 * NN; i += 512) gql[i] = gq[i];
    if (t < HH) {
        wf[t]       = w1g[t * 260 + 256];
        wf[64 + t]  = w1g[t * 260 + 257];
        wf[128 + t] = w1g[t * 260 + 258];
        wf[192 + t] = w1g[t * 260 + 259];
        wf[256 + t] = b1g[t];
        wf[320 + t] = w2g[t];
    }
    _Float16* sph = reinterpret_cast<_Float16*>(spk);
    if (t < NN) {
        xbuf[t] = 26.0f;
        sph[t] = (_Float16)(26.0f - 23.359f);
    }
    if (t < 8) td[0][t] = tdata[t];
    __syncthreads();
    if (t < HH)
        b1eff[t] = wf[256 + t] + wf[t] * td[0][4] + wf[64 + t] * td[0][5]
                 + wf[128 + t] * td[0][6] + wf[192 + t] * td[0][7];
    __syncthreads();

    const uint4* sp4 = reinterpret_cast<const uint4*>(spk);

    for (int k = 0; k < T; ++k) {
        const int cur = k & 1, nxt = cur ^ 1;
        float tdp = 0.0f;
        if (t >= 504 && k + 1 < T) tdp = tdata[(size_t)(k + 1) * 8 + (t - 504)];

        // ---- Phase A ----
        // policy hidden: hs = (w1/1.41) . x'  (8 conflict-free b64 broadcasts)
        float hs = 0.0f;
        {
            uint2 sx;
            sx = *reinterpret_cast<const uint2*>(spk + c2);       hs = dot2(p0,  sx.x, hs); hs = dot2(p1,  sx.y, hs);
            sx = *reinterpret_cast<const uint2*>(spk + c2 + 16);  hs = dot2(p2,  sx.x, hs); hs = dot2(p3,  sx.y, hs);
            sx = *reinterpret_cast<const uint2*>(spk + c2 + 32);  hs = dot2(p4,  sx.x, hs); hs = dot2(p5,  sx.y, hs);
            sx = *reinterpret_cast<const uint2*>(spk + c2 + 48);  hs = dot2(p6,  sx.x, hs); hs = dot2(p7,  sx.y, hs);
            sx = *reinterpret_cast<const uint2*>(spk + c2 + 64);  hs = dot2(p8,  sx.x, hs); hs = dot2(p9,  sx.y, hs);
            sx = *reinterpret_cast<const uint2*>(spk + c2 + 80);  hs = dot2(p10, sx.x, hs); hs = dot2(p11, sx.y, hs);
            sx = *reinterpret_cast<const uint2*>(spk + c2 + 96);  hs = dot2(p12, sx.x, hs); hs = dot2(p13, sx.y, hs);
            sx = *reinterpret_cast<const uint2*>(spk + c2 + 112); hs = dot2(p14, sx.x, hs); hs = dot2(p15, sx.y, hs);
        }
        hs += __shfl_xor(hs, 1); hs += __shfl_xor(hs, 2); hs += __shfl_xor(hs, 4);
        if ((t & 7) == 0) hid[jr] = tanhf(hs + b1eff[jr]);

        // E-matvec half-row: 64 dot2 on wave-uniform broadcast x'
        float ac0 = 0.f, ac1 = 0.f, ac2 = 0.f, ac3 = 0.f;
        {
            const uint4* xp = sp4 + hf * 16;
            uint4 q;
            q = xp[0];  ac0 = dot2(e0,  q.x, ac0); ac1 = dot2(e1,  q.y, ac1); ac2 = dot2(e2,  q.z, ac2); ac3 = dot2(e3,  q.w, ac3);
            q = xp[1];  ac0 = dot2(e4,  q.x, ac0); ac1 = dot2(e5,  q.y, ac1); ac2 = dot2(e6,  q.z, ac2); ac3 = dot2(e7,  q.w, ac3);
            q = xp[2];  ac0 = dot2(e8,  q.x, ac0); ac1 = dot2(e9,  q.y, ac1); ac2 = dot2(e10, q.z, ac2); ac3 = dot2(e11, q.w, ac3);
            q = xp[3];  ac0 = dot2(e12, q.x, ac0); ac1 = dot2(e13, q.y, ac1); ac2 = dot2(e14, q.z, ac2); ac3 = dot2(e15, q.w, ac3);
            q = xp[4];  ac0 = dot2(e16, q.x, ac0); ac1 = dot2(e17, q.y, ac1); ac2 = dot2(e18, q.z, ac2); ac3 = dot2(e19, q.w, ac3);
            q = xp[5];  ac0 = dot2(e20, q.x, ac0); ac1 = dot2(e21, q.y, ac1); ac2 = dot2(e22, q.z, ac2); ac3 = dot2(e23, q.w, ac3);
            q = xp[6];  ac0 = dot2(e24, q.x, ac0); ac1 = dot2(e25, q.y, ac1); ac2 = dot2(e26, q.z, ac2); ac3 = dot2(e27, q.w, ac3);
            q = xp[7];  ac0 = dot2(e28, q.x, ac0); ac1 = dot2(e29, q.y, ac1); ac2 = dot2(e30, q.z, ac2); ac3 = dot2(e31, q.w, ac3);
            q = xp[8];  ac0 = dot2(e32, q.x, ac0); ac1 = dot2(e33, q.y, ac1); ac2 = dot2(e34, q.z, ac2); ac3 = dot2(e35, q.w, ac3);
            q = xp[9];  ac0 = dot2(e36, q.x, ac0); ac1 = dot2(e37, q.y, ac1); ac2 = dot2(e38, q.z, ac2); ac3 = dot2(e39, q.w, ac3);
            q = xp[10]; ac0 = dot2(e40, q.x, ac0); ac1 = dot2(e41, q.y, ac1); ac2 = dot2(e42, q.z, ac2); ac3 = dot2(e43, q.w, ac3);
            q = xp[11]; ac0 = dot2(e44, q.x, ac0); ac1 = dot2(e45, q.y, ac1); ac2 = dot2(e46, q.z, ac2); ac3 = dot2(e47, q.w, ac3);
            q = xp[12]; ac0 = dot2(e48, q.x, ac0); ac1 = dot2(e49, q.y, ac1); ac2 = dot2(e50, q.z, ac2); ac3 = dot2(e51, q.w, ac3);
            q = xp[13]; ac0 = dot2(e52, q.x, ac0); ac1 = dot2(e53, q.y, ac1); ac2 = dot2(e54, q.z, ac2); ac3 = dot2(e55, q.w, ac3);
            q = xp[14]; ac0 = dot2(e56, q.x, ac0); ac1 = dot2(e57, q.y, ac1); ac2 = dot2(e58, q.z, ac2); ac3 = dot2(e59, q.w, ac3);
            q = xp[15]; ac0 = dot2(e60, q.x, ac0); ac1 = dot2(e61, q.y, ac1); ac2 = dot2(e62, q.z, ac2); ac3 = dot2(e63, q.w, ac3);
        }
        part[hf][r] = (ac0 + ac1) + (ac2 + ac3);

        if (t < NN) out[(size_t)k * NN + t] = xbuf[t];
        if (t >= 504) td[nxt][t - 504] = tdp;
        asm volatile("s_waitcnt lgkmcnt(0)\ns_barrier" ::: "memory");

        // ---- Phase B ----
        if (t < NN) {
            float v = wf[320 + lane] * hid[lane];
            v += __shfl_xor(v, 1);  v += __shfl_xor(v, 2);  v += __shfl_xor(v, 4);
            v += __shfl_xor(v, 8);  v += __shfl_xor(v, 16); v += __shfl_xor(v, 32);
            float aS = sigm(v);
            float S0 = td[cur][0], S1 = td[cur][1], S2 = td[cur][2], S3 = td[cur][3];
            float y = (part[0][t] + part[1][t]) * 0.015625f;   // /64 scale
            float xn = xbuf[t] + y + gql[1280 + t]
                     + S0 * gql[t] + S1 * gql[256 + t] + S2 * gql[512 + t]
                     + S3 * gql[768 + t] - aS * gql[1024 + t];
            xbuf[t] = xn;
            sph[t] = (_Float16)(xn - 23.359f);
        } else if (t < 320 && k + 1 < T) {
            int j = t - 256;
            b1eff[j] = wf[256 + j] + wf[j] * td[nxt][4] + wf[64 + j] * td[nxt][5]
                     + wf[128 + j] * td[nxt][6] + wf[192 + j] * td[nxt][7];
        }
        asm volatile("s_waitcnt lgkmcnt(0)\ns_barrier" ::: "memory");
    }
}

extern "C" void kernel_launch(void* const* d_in, const int* in_sizes, int n_in,
                              void* d_out, int out_size, void* d_ws, size_t ws_size,
                              hipStream_t stream)
{
    (void)n_in; (void)out_size; (void)ws_size;
    const float* tev     = (const float*)d_in[0];
    const float* A       = (const float*)d_in[1];
    const float* B       = (const float*)d_in[2];
    const float* cooling = (const float*)d_in[3];
    const float* w1      = (const float*)d_in[4];
    const float* b1      = (const float*)d_in[5];
    const float* w2      = (const float*)d_in[6];
    const float* tts     = (const float*)d_in[7];
    const float* tvals   = (const float*)d_in[8];
    const int T     = in_sizes[0];
    const int ntout = in_sizes[7];

    float* out = (float*)d_out;
    float* ws  = (float*)d_ws;
    float*  R    = ws;                          // 65536 floats
    float*  gq   = ws + 65536;                  // 1536 floats
    uint32* w1pk = (uint32*)(ws + 67072);       // 8192 dwords
    float*  td   = ws + 75264;                  // T*8 floats
    float* P1 = out;                            // GEMM ping-pong (rewritten by k_main)
    float* P2 = out + 65536;
    size_t outN = (size_t)T * NN;
    uint32* Epk = (uint32*)(out + outN - 32768);  // 128 KB tail, read before overwritten

    hipLaunchKernelGGL(k_affine, dim3(256), dim3(256), 0, stream, A, P1, tev, 4);
    hipLaunchKernelGGL(k_gemm,   dim3(256), dim3(256), 0, stream, A, P1, P2, tev, 3);
    hipLaunchKernelGGL(k_gemm,   dim3(256), dim3(256), 0, stream, A, P2, P1, tev, 2);
    hipLaunchKernelGGL(k_gemm,   dim3(256), dim3(256), 0, stream, A, P1, R,  tev, 1);
    hipLaunchKernelGGL(k_packE,  dim3(128), dim3(256), 0, stream, R, Epk);
    hipLaunchKernelGGL(k_packW,  dim3(32),  dim3(256), 0, stream, w1, w1pk);
    hipLaunchKernelGGL(k_prep_vec, dim3(1), dim3(256), 0, stream, A, B, cooling, tev, R, gq);
    hipLaunchKernelGGL(k_time, dim3((T + 255) / 256), dim3(256), 0, stream,
                       tev, tts, tvals, td, T, ntout);
    hipLaunchKernelGGL(k_main, dim3(1), dim3(512), 0, stream,
                       td, Epk, w1pk, gq, w1, b1, w2, out, T);
}